// Round 9
// baseline (135.756 us; speedup 1.0000x reference)
//
#include <hip/hip_runtime.h>
#include <math.h>

typedef _Float16 f16_t;
typedef __attribute__((ext_vector_type(8))) _Float16 f16x8;
typedef __attribute__((ext_vector_type(4))) float f32x4;

#define NTOK 131072
#define MT   64       // tokens per block
#define TPB  128      // 2 waves; each wave owns 32 tokens (M=32 tile)
#define RP16 72       // relay pitch (f16)
#define OP32 68       // out-stage pitch (f32)
#define SLABB 4608    // per-wave slab: relay 32*72*2

// ws layout (f16 elems)
#define OFF_KEY 0
#define OFF_VAL 4096
#define OFF_T   8192
#define OFF_D1  40960
#define OFF_D2  45056
#define OFF_D3  47104
#define WTOT    49152

__device__ __forceinline__ f32x4 mfma1(f16x8 a, f16x8 b, f32x4 c) {
    return __builtin_amdgcn_mfma_f32_16x16x32_f16(a, b, c, 0, 0, 0);
}

// ---- DPP 16-lane butterfly reductions (VALU, no LDS round-trips) ----------
#define DPPF(x, C) __int_as_float(__builtin_amdgcn_update_dpp( \
    0, __float_as_int(x), (C), 0xF, 0xF, true))

__device__ __forceinline__ void red16_sum4(f32x4& x) {
#pragma unroll
    for (int e = 0; e < 4; ++e) {
        float v = x[e];
        v += DPPF(v, 0xB1);
        v += DPPF(v, 0x4E);
        v += DPPF(v, 0x141);
        v += DPPF(v, 0x140);
        x[e] = v;
    }
}
__device__ __forceinline__ void red16_max4(f32x4& x) {
#pragma unroll
    for (int e = 0; e < 4; ++e) {
        float v = x[e];
        v = fmaxf(v, DPPF(v, 0xB1));
        v = fmaxf(v, DPPF(v, 0x4E));
        v = fmaxf(v, DPPF(v, 0x141));
        v = fmaxf(v, DPPF(v, 0x140));
        x[e] = v;
    }
}

struct B2 { f16x8 b0, b1; };

// LDS B-fragment read, XOR-swizzled (128B-row panels). Proven conflict-clean in R3.
__device__ __forceinline__ B2 loadB_lds(const f16_t* __restrict__ b, int c, int l15, int quad) {
    const char* base = (const char*)b;
    int o0 = (16 * c + l15) * 128 + quad * 16;
    int sw = (l15 & 7) << 4;
    B2 r;
    r.b0 = *(const f16x8*)(base + (o0 ^ sw));
    r.b1 = *(const f16x8*)(base + ((o0 + 64) ^ sw));
    return r;
}

#define GEMML(buf, c, a00, a01, a10, a11, acc0, acc1) do {        \
    B2 Bf = loadB_lds((buf), (c), l15, quad);                      \
    acc0 = mfma1(a01, Bf.b1, mfma1(a00, Bf.b0, acc0));             \
    acc1 = mfma1(a11, Bf.b1, mfma1(a10, Bf.b0, acc1));             \
} while (0)

// async global->LDS DMA, 16B/lane; LDS dest = wave-uniform base + lane*16
__device__ __forceinline__ void gl_lds16(const void* g, void* l) {
    __builtin_amdgcn_global_load_lds(
        (const __attribute__((address_space(1))) unsigned int*)g,
        (__attribute__((address_space(3))) unsigned int*)l, 16, 0, 0);
}

// Stage an 8KB 128B-row panel (TPB=128 -> 4 loads/thread). Swizzle applied as
// inverse perm on the GLOBAL src: LDS[row][col ^ ((row&7)<<4)] = G[row][col].
// (o & ~1023) = wave-uniform 1KB segment base (64 lanes x 16B).
__device__ __forceinline__ void stage8k(const f16_t* __restrict__ gsrc, f16_t* lbuf, int tid) {
#pragma unroll
    for (int i = 0; i < 4; ++i) {
        int o = (i * TPB + tid) * 16;
        int g = o ^ (((o >> 7) & 7) << 4);
        gl_lds16((const char*)gsrc + g, (char*)lbuf + (o & ~1023));
    }
}
__device__ __forceinline__ void stage4k_r128(const f16_t* __restrict__ gsrc, f16_t* lbuf, int tid) {
#pragma unroll
    for (int i = 0; i < 2; ++i) {
        int o = (i * TPB + tid) * 16;
        int g = o ^ (((o >> 7) & 7) << 4);
        gl_lds16((const char*)gsrc + g, (char*)lbuf + (o & ~1023));
    }
}
// 64B-row panel (d3): swizzle XORs bits 4-5 with row>>1
__device__ __forceinline__ void stage4k_r64(const f16_t* __restrict__ gsrc, f16_t* lbuf, int tid) {
#pragma unroll
    for (int i = 0; i < 2; ++i) {
        int o = (i * TPB + tid) * 16;
        int g = o ^ (((o >> 7) & 3) << 4);
        gl_lds16((const char*)gsrc + g, (char*)lbuf + (o & ~1023));
    }
}

// counted vmcnt + raw barrier (NEVER __syncthreads: it drains vmcnt(0))
#define VMW4() asm volatile("s_waitcnt vmcnt(4)" ::: "memory")
#define VMW0() asm volatile("s_waitcnt vmcnt(0)" ::: "memory")
#define BAR()  do { __builtin_amdgcn_s_barrier(); asm volatile("" ::: "memory"); } while (0)
// BUFFER-RELEASE barrier (R8 race fix): ISA rule "s_waitcnt first if data dep".
// A bare s_barrier proves DS reads were ISSUED, not COMPLETE; an in-flight
// ds_read can sample LDS after the next stage's DMA overwrite lands.
// Drain lgkmcnt(0) so all waves' DS ops are complete before buffer reuse.
#define BARREL() do { asm volatile("s_waitcnt lgkmcnt(0)" ::: "memory"); \
                      __builtin_amdgcn_s_barrier(); \
                      asm volatile("" ::: "memory"); } while (0)

// ---------------- prep: transpose all weights into ws as fp16 --------------
__global__ __launch_bounds__(256)
void prep_w(const float* __restrict__ keyW, const float* __restrict__ valW,
            const float* __restrict__ TW,   const float* __restrict__ TB,
            const float* __restrict__ d1W,  const float* __restrict__ d2W,
            const float* __restrict__ d3W,  f16_t* __restrict__ wsf)
{
    int idx = blockIdx.x * 256 + threadIdx.x;
    if (idx >= WTOT) return;
    float src;
    if (idx < OFF_VAL) {
        int r = idx - OFF_KEY, n = r >> 6, j = r & 63;
        src = keyW[j * 64 + n];
    } else if (idx < OFF_T) {
        int r = idx - OFF_VAL, n = r >> 6, j = r & 63;
        src = valW[j * 64 + n];
    } else if (idx < OFF_D1) {
        int r = idx - OFF_T, p = r >> 12, q = r & 4095;
        src = (p < 7) ? TW[p * 4096 + q] : TB[q];
    } else if (idx < OFF_D2) {
        int r = idx - OFF_D1, n = r >> 6, j = r & 63;
        src = d1W[j * 64 + n];
    } else if (idx < OFF_D3) {
        int r = idx - OFF_D2, n = r >> 6, j = r & 63;
        src = d2W[j * 32 + n];
    } else {
        int r = idx - OFF_D3, n = r >> 5, j = r & 31;
        src = d3W[j * 64 + n];
    }
    wsf[idx] = (f16_t)src;
}

// per-row-tile front: k|v GEMM (LDS-staged) + softmax + att + normalize + relay.
__device__ __forceinline__ void front_rt(
    f16_t* __restrict__ Rf,
    const f16_t* __restrict__ keyb, const f16_t* __restrict__ valb,
    int l15, int quad, int rtb,
    f16x8 a0, f16x8 a1,
    f32x4 q0, f32x4 q1, f32x4 q2, f32x4 q3,
    f32x4 kbv, f32x4 vbv, float sc)
{
    f32x4 k0 = {}, k1 = {}, k2 = {}, k3 = {}, v0 = {}, v1 = {}, v2 = {}, v3 = {};
    { B2 B = loadB_lds(keyb, 0, l15, quad); k0 = mfma1(a1, B.b1, mfma1(a0, B.b0, k0)); }
    { B2 B = loadB_lds(keyb, 1, l15, quad); k1 = mfma1(a1, B.b1, mfma1(a0, B.b0, k1)); }
    { B2 B = loadB_lds(keyb, 2, l15, quad); k2 = mfma1(a1, B.b1, mfma1(a0, B.b0, k2)); }
    { B2 B = loadB_lds(keyb, 3, l15, quad); k3 = mfma1(a1, B.b1, mfma1(a0, B.b0, k3)); }
    { B2 B = loadB_lds(valb, 0, l15, quad); v0 = mfma1(a1, B.b1, mfma1(a0, B.b0, v0)); }
    { B2 B = loadB_lds(valb, 1, l15, quad); v1 = mfma1(a1, B.b1, mfma1(a0, B.b0, v1)); }
    { B2 B = loadB_lds(valb, 2, l15, quad); v2 = mfma1(a1, B.b1, mfma1(a0, B.b0, v2)); }
    { B2 B = loadB_lds(valb, 3, l15, quad); v3 = mfma1(a1, B.b1, mfma1(a0, B.b0, v3)); }

    f32x4 sv0 = (v0 + vbv[0]) * sc;
    f32x4 sv1 = (v1 + vbv[1]) * sc;
    f32x4 sv2 = (v2 + vbv[2]) * sc;
    f32x4 sv3 = (v3 + vbv[3]) * sc;

    f32x4 mx;
#pragma unroll
    for (int e = 0; e < 4; ++e)
        mx[e] = fmaxf(fmaxf(sv0[e], sv1[e]), fmaxf(sv2[e], sv3[e]));
    red16_max4(mx);
#pragma unroll
    for (int e = 0; e < 4; ++e) {
        sv0[e] = __expf(sv0[e] - mx[e]);
        sv1[e] = __expf(sv1[e] - mx[e]);
        sv2[e] = __expf(sv2[e] - mx[e]);
        sv3[e] = __expf(sv3[e] - mx[e]);
    }
    f32x4 se = sv0 + sv1 + sv2 + sv3;
    red16_sum4(se);

    f32x4 at0 = q0 * (k0 + kbv[0]);
    f32x4 at1 = q1 * (k1 + kbv[1]);
    f32x4 at2 = q2 * (k2 + kbv[2]);
    f32x4 at3 = q3 * (k3 + kbv[3]);
    f32x4 nr = at0 * at0 + at1 * at1 + at2 * at2 + at3 * at3;
    red16_sum4(nr);

    f32x4 fac;
#pragma unroll
    for (int e = 0; e < 4; ++e)
        fac[e] = 1.0f / (fmaxf(sqrtf(nr[e]), 1e-8f) * se[e]);

#pragma unroll
    for (int e = 0; e < 4; ++e) {
        f16_t* rr = Rf + (rtb + quad * 4 + e) * RP16 + l15;
        rr[0]  = (f16_t)(at0[e] * sv0[e] * fac[e]);
        rr[16] = (f16_t)(at1[e] * sv1[e] * fac[e]);
        rr[32] = (f16_t)(at2[e] * sv2[e] * fac[e]);
        rr[48] = (f16_t)(at3[e] * sv3[e] * fac[e]);
    }
}

// 32-row d1 pass: h1 = relu(x @ d1 + b1), relay in-place
__device__ __forceinline__ void d1_rt(f16_t* __restrict__ Rf, const f16_t* __restrict__ wb,
                                      int l15, int quad, int rtb, f32x4 b1v)
{
    f16x8 x00 = *(const f16x8*)(Rf + (rtb + l15) * RP16 + quad * 8);
    f16x8 x01 = *(const f16x8*)(Rf + (rtb + l15) * RP16 + 32 + quad * 8);
    f16x8 x10 = *(const f16x8*)(Rf + (rtb + 16 + l15) * RP16 + quad * 8);
    f16x8 x11 = *(const f16x8*)(Rf + (rtb + 16 + l15) * RP16 + 32 + quad * 8);
    f32x4 h00 = {}, h01 = {}, h02 = {}, h03 = {};
    f32x4 h10 = {}, h11 = {}, h12 = {}, h13 = {};
    GEMML(wb, 0, x00, x01, x10, x11, h00, h10);
    GEMML(wb, 1, x00, x01, x10, x11, h01, h11);
    GEMML(wb, 2, x00, x01, x10, x11, h02, h12);
    GEMML(wb, 3, x00, x01, x10, x11, h03, h13);
#pragma unroll
    for (int e = 0; e < 4; ++e) {
        f16_t* r0 = Rf + (rtb + quad * 4 + e) * RP16 + l15;
        r0[0]  = (f16_t)fmaxf(h00[e] + b1v[0], 0.f);
        r0[16] = (f16_t)fmaxf(h01[e] + b1v[1], 0.f);
        r0[32] = (f16_t)fmaxf(h02[e] + b1v[2], 0.f);
        r0[48] = (f16_t)fmaxf(h03[e] + b1v[3], 0.f);
        f16_t* r1 = Rf + (rtb + 16 + quad * 4 + e) * RP16 + l15;
        r1[0]  = (f16_t)fmaxf(h10[e] + b1v[0], 0.f);
        r1[16] = (f16_t)fmaxf(h11[e] + b1v[1], 0.f);
        r1[32] = (f16_t)fmaxf(h12[e] + b1v[2], 0.f);
        r1[48] = (f16_t)fmaxf(h13[e] + b1v[3], 0.f);
    }
}

// 32-row d2 pass: h2 = relu(h1 @ d2 + b2), 32 cols
__device__ __forceinline__ void d2_rt(f16_t* __restrict__ Rf, const f16_t* __restrict__ wb,
                                      int l15, int quad, int rtb, float b20, float b21)
{
    f16x8 x00 = *(const f16x8*)(Rf + (rtb + l15) * RP16 + quad * 8);
    f16x8 x01 = *(const f16x8*)(Rf + (rtb + l15) * RP16 + 32 + quad * 8);
    f16x8 x10 = *(const f16x8*)(Rf + (rtb + 16 + l15) * RP16 + quad * 8);
    f16x8 x11 = *(const f16x8*)(Rf + (rtb + 16 + l15) * RP16 + 32 + quad * 8);
    f32x4 g00 = {}, g01 = {}, g10 = {}, g11 = {};
    GEMML(wb, 0, x00, x01, x10, x11, g00, g10);
    GEMML(wb, 1, x00, x01, x10, x11, g01, g11);
#pragma unroll
    for (int e = 0; e < 4; ++e) {
        f16_t* r0 = Rf + (rtb + quad * 4 + e) * RP16 + l15;
        r0[0]  = (f16_t)fmaxf(g00[e] + b20, 0.f);
        r0[16] = (f16_t)fmaxf(g01[e] + b21, 0.f);
        f16_t* r1 = Rf + (rtb + 16 + quad * 4 + e) * RP16 + l15;
        r1[0]  = (f16_t)fmaxf(g10[e] + b20, 0.f);
        r1[16] = (f16_t)fmaxf(g11[e] + b21, 0.f);
    }
}

// 32-row d3 pass: out = h2 @ d3 + b3 (K=32) -> two 16-row staged stores.
__device__ __forceinline__ void d3_rt(f16_t* __restrict__ Rf, float* __restrict__ Of,
                                      const char* __restrict__ d3b,
                                      int l15, int quad, int lane, int rtb,
                                      f32x4 b3v, float* __restrict__ obase)
{
    f16x8 a30 = *(const f16x8*)(Rf + (rtb + l15) * RP16 + quad * 8);
    f16x8 a31 = *(const f16x8*)(Rf + (rtb + 16 + l15) * RP16 + quad * 8);
    const int sw3 = ((l15 >> 1) & 3) << 4;
#pragma unroll
    for (int h = 0; h < 2; ++h) {
        const f16x8 a3 = h ? a31 : a30;
#pragma unroll
        for (int c = 0; c < 4; ++c) {
            int o3 = (16 * c + l15) * 64 + quad * 16;
            f16x8 bw = *(const f16x8*)(d3b + (o3 ^ sw3));
            f32x4 z = {};
            f32x4 o = mfma1(a3, bw, z);
#pragma unroll
            for (int e = 0; e < 4; ++e)
                Of[(quad * 4 + e) * OP32 + 16 * c + l15] = o[e] + b3v[c];
        }
#pragma unroll
        for (int i = 0; i < 4; ++i) {
            const int r4 = i * 4 + quad;
            f32x4 v = *(const f32x4*)(Of + r4 * OP32 + l15 * 4);
            *(f32x4*)(obase + rtb * 64 + h * 1024 + i * 256 + lane * 4) = v;
        }
    }
}

// ------- main: MT=64/TPB=128, M=32/wave -> LDS 26624 B -> 6 blocks/CU ------
// 12 waves/CU: +50% TLP. BARREL (lgkmcnt-drained barrier) at every point a
// WB buffer is released for DMA overwrite (R8 race fix).
__global__ __launch_bounds__(TPB, 2)   // natural regalloc; spill tripwire = WRITE_SIZE
void fused_mfma(const float* __restrict__ kv_in, const float* __restrict__ q_in,
                const float* __restrict__ keyB,  const float* __restrict__ valB,
                const float* __restrict__ d1B,   const float* __restrict__ d2B,
                const float* __restrict__ d3B,   const float* __restrict__ scale_p,
                const f16_t* __restrict__ wsf,   float* __restrict__ out)
{
    __shared__ __align__(16) unsigned char Slab[2][SLABB];   // 9216 B (wave-private)
    __shared__ __align__(16) f16_t Qs16[MT][8];              // 1024 B (f16 q'-table)
    __shared__ __align__(16) f16_t WB[2][4096];              // 16384 B -> 26624 total

    const int tid  = threadIdx.x;
    const int wv   = tid >> 6, lane = tid & 63;
    const int quad = lane >> 4, l15 = lane & 15;
    const int RB   = wv * 32;
    const long t0  = (long)blockIdx.x * MT;

    f16_t* __restrict__ Rf = (f16_t*)Slab[wv];
    float* __restrict__ Of = (float*)Slab[wv];

    // ---- relay FIRST (its vmcnt drain not blocked behind weight DMA) ----
    {
        const int r = lane >> 1, half = lane & 1;
        const float4* p4 = (const float4*)(kv_in + (t0 + RB + r) * 64 + half * 32);
        f16_t* dst = Rf + r * RP16 + half * 32;
#pragma unroll
        for (int b = 0; b < 4; ++b) {
            float4 f0 = p4[2 * b], f1 = p4[2 * b + 1];
            f16x8 h;
            h[0] = (f16_t)f0.x; h[1] = (f16_t)f0.y; h[2] = (f16_t)f0.z; h[3] = (f16_t)f0.w;
            h[4] = (f16_t)f1.x; h[5] = (f16_t)f1.y; h[6] = (f16_t)f1.z; h[7] = (f16_t)f1.w;
            *(f16x8*)(dst + 8 * b) = h;
        }
    }
    // q' -> Qs16 as f16 [token][plane] (wave-private rows, 32 tokens/wave)
    if (lane < 32) {
        const float* qp = q_in + (t0 + RB + lane) * 7;
        f16x8 qh;
#pragma unroll
        for (int p = 0; p < 7; ++p) qh[p] = (f16_t)qp[p];
        qh[7] = (f16_t)1.0f;
        *(f16x8*)&Qs16[RB + lane][0] = qh;
    }
    // small params (L2 hits, consumed late)
    f32x4 kbv, vbv, b1v, b3v;
#pragma unroll
    for (int c = 0; c < 4; ++c) {
        kbv[c] = keyB[16 * c + l15];  vbv[c] = valB[16 * c + l15];
        b1v[c] = d1B[16 * c + l15];   b3v[c] = d3B[16 * c + l15];
    }
    const float b20 = d2B[l15], b21 = d2B[16 + l15];
    const float sc = scale_p[0];

    // async DMA of T planes 0,1 (newest in queue -> VMW4 at p=0 waits T0 only)
    stage8k(wsf + OFF_T + 0 * 4096, WB[0], tid);
    stage8k(wsf + OFF_T + 1 * 4096, WB[1], tid);

    // ---- A-fragments: 2 row-tiles x 2 halves (named) ----
    f16x8 ah00 = *(const f16x8*)(Rf + l15 * RP16 + quad * 8);
    f16x8 ah01 = *(const f16x8*)(Rf + l15 * RP16 + 32 + quad * 8);
    f16x8 ah10 = *(const f16x8*)(Rf + (16 + l15) * RP16 + quad * 8);
    f16x8 ah11 = *(const f16x8*)(Rf + (16 + l15) * RP16 + 32 + quad * 8);

    // ---- T stage as one K=512 GEMM, 2-buffer pipeline ----
    // iter p: VMW4 (plane p landed; plane p+1's 4 loads in flight); BAR;
    // compute from WB[p&1]; BARREL (DS reads COMPLETE in all waves);
    // stage plane p+2 into WB[p&1].
    f32x4 q00 = {}, q01 = {}, q02 = {}, q03 = {};
    f32x4 q10 = {}, q11 = {}, q12 = {}, q13 = {};
#pragma unroll 1
    for (int p = 0; p < 8; ++p) {
        const f16_t* tb = WB[p & 1];
        VMW4(); BAR();
        // per-row-tile q' scales (quad-broadcast ds_read_u16, wave-private)
        f16_t s0 = Qs16[RB + l15][p];
        f16_t s1 = Qs16[RB + 16 + l15][p];
        f16x8 w0 = {s0, s0, s0, s0, s0, s0, s0, s0};
        f16x8 w1 = {s1, s1, s1, s1, s1, s1, s1, s1};
        f16x8 sa00 = ah00 * w0, sa01 = ah01 * w0;
        f16x8 sa10 = ah10 * w1, sa11 = ah11 * w1;
        { B2 B = loadB_lds(tb, 0, l15, quad);
          q00 = mfma1(sa01, B.b1, mfma1(sa00, B.b0, q00));
          q10 = mfma1(sa11, B.b1, mfma1(sa10, B.b0, q10)); }
        { B2 B = loadB_lds(tb, 1, l15, quad);
          q01 = mfma1(sa01, B.b1, mfma1(sa00, B.b0, q01));
          q11 = mfma1(sa11, B.b1, mfma1(sa10, B.b0, q11)); }
        { B2 B = loadB_lds(tb, 2, l15, quad);
          q02 = mfma1(sa01, B.b1, mfma1(sa00, B.b0, q02));
          q12 = mfma1(sa11, B.b1, mfma1(sa10, B.b0, q12)); }
        { B2 B = loadB_lds(tb, 3, l15, quad);
          q03 = mfma1(sa01, B.b1, mfma1(sa00, B.b0, q03));
          q13 = mfma1(sa11, B.b1, mfma1(sa10, B.b0, q13)); }
        BARREL();   // release WB[p&1] for overwrite (reads drained, all waves)
        const f16_t* nsrc = (p < 6) ? (wsf + OFF_T + (p + 2) * 4096)
                                    : ((p == 6) ? (wsf + OFF_KEY) : (wsf + OFF_VAL));
        stage8k(nsrc, WB[p & 1], tid);
    }
    VMW0(); BAR();   // KEY in WB[0], VAL in WB[1] ready

    // ---- fronts: 2 row-tiles (k|v + softmax + att + relay) ----
    front_rt(Rf, WB[0], WB[1], l15, quad, 0,  ah00, ah01, q00, q01, q02, q03, kbv, vbv, sc);
    front_rt(Rf, WB[0], WB[1], l15, quad, 16, ah10, ah11, q10, q11, q12, q13, kbv, vbv, sc);
    BARREL();        // release KEY/VAL panels (reads drained, all waves)
    stage8k(wsf + OFF_D1, WB[0], tid);                 // d1 -> WB[0] (8KB)
    stage4k_r128(wsf + OFF_D2, WB[1], tid);            // d2 -> WB[1][0:2048] (4KB)
    stage4k_r64 (wsf + OFF_D3, WB[1] + 2048, tid);     // d3 -> WB[1][2048:] (4KB, 64B rows)
    VMW0(); BAR();

    // ---- d-chain: one 32-row pass per layer (wave-private, no barriers) ----
    d1_rt(Rf, WB[0], l15, quad, 0, b1v);
    d2_rt(Rf, WB[1], l15, quad, 0, b20, b21);

    float* __restrict__ obase = out + (t0 + RB) * 64;
    const char* d3b = (const char*)(&WB[1][2048]);
    d3_rt(Rf, Of, d3b, l15, quad, lane, 0, b3v, obase);
}

extern "C" void kernel_launch(void* const* d_in, const int* in_sizes, int n_in,
                              void* d_out, int out_size, void* d_ws, size_t ws_size,
                              hipStream_t stream) {
    (void)in_sizes; (void)n_in; (void)out_size; (void)ws_size;
    const float* kv_in = (const float*)d_in[0];
    const float* q_in  = (const float*)d_in[1];
    const float* keyW  = (const float*)d_in[2];
    const float* keyB  = (const float*)d_in[3];
    const float* valW  = (const float*)d_in[4];
    const float* valB  = (const float*)d_in[5];
    const float* TW    = (const float*)d_in[6];
    const float* TB    = (const float*)d_in[7];
    const float* d1W   = (const float*)d_in[8];
    const float* d1B   = (const float*)d_in[9];
    const float* d2W   = (const float*)d_in[10];
    const float* d2B   = (const float*)d_in[11];
    const float* d3W   = (const float*)d_in[12];
    const float* d3B   = (const float*)d_in[13];
    const float* scale = (const float*)d_in[14];
    f16_t* wsf = (f16_t*)d_ws;
    float* outp = (float*)d_out;

    prep_w<<<(WTOT + 255) / 256, 256, 0, stream>>>(keyW, valW, TW, TB, d1W, d2W, d3W, wsf);
    fused_mfma<<<NTOK / MT, TPB, 0, stream>>>(kv_in, q_in, keyB, valB,
                                              d1B, d2B, d3B, scale, wsf, outp);
}

// Round 11
// 134.672 us; speedup vs baseline: 1.0080x; 1.0080x over previous
//
#include <hip/hip_runtime.h>
#include <math.h>

typedef _Float16 f16_t;
typedef __attribute__((ext_vector_type(8))) _Float16 f16x8;
typedef __attribute__((ext_vector_type(4))) float f32x4;

#define NTOK  131072
#define MT    256     // tokens per tile (8 waves x 32 rows)
#define TPB   512     // 8 waves
#define TILES 2       // tiles per block
#define NBLK  (NTOK / (MT * TILES))   // 256 blocks = 1 per CU
#define RP16  72      // relay pitch (f16)
#define OP32  68      // out-stage pitch (f32)
#define SLABB 4608    // per-wave slab: relay 32*72*2

// ws layout (f16 elems) — mirrored 1:1 into resident LDS
#define OFF_KEY 0
#define OFF_VAL 4096
#define OFF_T   8192
#define OFF_D1  40960
#define OFF_D2  45056
#define OFF_D3  47104
#define WTOT    49152
// byte split: [0, 94208) = 128B-row panels (KEY,VAL,T0..7,D1,D2); [94208, 98304) = D3 (64B rows)

__device__ __forceinline__ f32x4 mfma1(f16x8 a, f16x8 b, f32x4 c) {
    return __builtin_amdgcn_mfma_f32_16x16x32_f16(a, b, c, 0, 0, 0);
}

// ---- DPP 16-lane butterfly reductions (VALU, no LDS round-trips) ----------
#define DPPF(x, C) __int_as_float(__builtin_amdgcn_update_dpp( \
    0, __float_as_int(x), (C), 0xF, 0xF, true))

__device__ __forceinline__ void red16_sum4(f32x4& x) {
#pragma unroll
    for (int e = 0; e < 4; ++e) {
        float v = x[e];
        v += DPPF(v, 0xB1);
        v += DPPF(v, 0x4E);
        v += DPPF(v, 0x141);
        v += DPPF(v, 0x140);
        x[e] = v;
    }
}
__device__ __forceinline__ void red16_max4(f32x4& x) {
#pragma unroll
    for (int e = 0; e < 4; ++e) {
        float v = x[e];
        v = fmaxf(v, DPPF(v, 0xB1));
        v = fmaxf(v, DPPF(v, 0x4E));
        v = fmaxf(v, DPPF(v, 0x141));
        v = fmaxf(v, DPPF(v, 0x140));
        x[e] = v;
    }
}

struct B2 { f16x8 b0, b1; };

// LDS B-fragment read, XOR-swizzled (128B-row panels). Conflict-clean (R3).
__device__ __forceinline__ B2 loadB_lds(const f16_t* __restrict__ b, int c, int l15, int quad) {
    const char* base = (const char*)b;
    int o0 = (16 * c + l15) * 128 + quad * 16;
    int sw = (l15 & 7) << 4;
    B2 r;
    r.b0 = *(const f16x8*)(base + (o0 ^ sw));
    r.b1 = *(const f16x8*)(base + ((o0 + 64) ^ sw));
    return r;
}

#define GEMML(buf, c, a00, a01, a10, a11, acc0, acc1) do {        \
    B2 Bf = loadB_lds((buf), (c), l15, quad);                      \
    acc0 = mfma1(a01, Bf.b1, mfma1(a00, Bf.b0, acc0));             \
    acc1 = mfma1(a11, Bf.b1, mfma1(a10, Bf.b0, acc1));             \
} while (0)

// async global->LDS DMA, 16B/lane; LDS dest = wave-uniform base + lane*16
__device__ __forceinline__ void gl_lds16(const void* g, void* l) {
    __builtin_amdgcn_global_load_lds(
        (const __attribute__((address_space(1))) unsigned int*)g,
        (__attribute__((address_space(3))) unsigned int*)l, 16, 0, 0);
}

// ONE-TIME weight DMA: entire 96KB ws -> resident LDS, per-panel XOR swizzle
// applied as inverse perm on the GLOBAL source (both-sides-or-neither rule).
// All panel starts are 1KB-multiples, so absolute (o>>7)&7 == panel-local row&7.
__device__ __forceinline__ void stage_all(const f16_t* __restrict__ wsf,
                                          f16_t* Wl, int tid) {
#pragma unroll
    for (int i = 0; i < 12; ++i) {
        int idx = i * TPB + tid;                 // 16B chunks of [0, 94208)
        if (idx < 5888) {
            int o = idx * 16;
            int g = o ^ (((o >> 7) & 7) << 4);   // 128B-row swizzle
            gl_lds16((const char*)wsf + g, (char*)Wl + (o & ~1023));
        }
    }
    if (tid < 256) {                             // D3: 4KB, 64B rows
        int o = tid * 16;
        int g = o ^ (((o >> 7) & 3) << 4);
        gl_lds16((const char*)wsf + 94208 + g, (char*)Wl + 94208 + (o & ~1023));
    }
}

#define VMW0() asm volatile("s_waitcnt vmcnt(0)" ::: "memory")
#define BAR()  do { __builtin_amdgcn_s_barrier(); asm volatile("" ::: "memory"); } while (0)

// ---------------- prep: transpose all weights into ws as fp16 --------------
__global__ __launch_bounds__(256)
void prep_w(const float* __restrict__ keyW, const float* __restrict__ valW,
            const float* __restrict__ TW,   const float* __restrict__ TB,
            const float* __restrict__ d1W,  const float* __restrict__ d2W,
            const float* __restrict__ d3W,  f16_t* __restrict__ wsf)
{
    int idx = blockIdx.x * 256 + threadIdx.x;
    if (idx >= WTOT) return;
    float src;
    if (idx < OFF_VAL) {
        int r = idx - OFF_KEY, n = r >> 6, j = r & 63;
        src = keyW[j * 64 + n];
    } else if (idx < OFF_T) {
        int r = idx - OFF_VAL, n = r >> 6, j = r & 63;
        src = valW[j * 64 + n];
    } else if (idx < OFF_D1) {
        int r = idx - OFF_T, p = r >> 12, q = r & 4095;
        src = (p < 7) ? TW[p * 4096 + q] : TB[q];
    } else if (idx < OFF_D2) {
        int r = idx - OFF_D1, n = r >> 6, j = r & 63;
        src = d1W[j * 64 + n];
    } else if (idx < OFF_D3) {
        int r = idx - OFF_D2, n = r >> 6, j = r & 63;
        src = d2W[j * 32 + n];
    } else {
        int r = idx - OFF_D3, n = r >> 5, j = r & 31;
        src = d3W[j * 64 + n];
    }
    wsf[idx] = (f16_t)src;
}

// per-row-tile front: k|v GEMM (resident LDS) + softmax + att + normalize + relay.
__device__ __forceinline__ void front_rt(
    f16_t* __restrict__ Rf,
    const f16_t* __restrict__ keyb, const f16_t* __restrict__ valb,
    int l15, int quad, int rtb,
    f16x8 a0, f16x8 a1,
    f32x4 q0, f32x4 q1, f32x4 q2, f32x4 q3,
    f32x4 kbv, f32x4 vbv, float sc)
{
    f32x4 k0 = {}, k1 = {}, k2 = {}, k3 = {}, v0 = {}, v1 = {}, v2 = {}, v3 = {};
    { B2 B = loadB_lds(keyb, 0, l15, quad); k0 = mfma1(a1, B.b1, mfma1(a0, B.b0, k0)); }
    { B2 B = loadB_lds(keyb, 1, l15, quad); k1 = mfma1(a1, B.b1, mfma1(a0, B.b0, k1)); }
    { B2 B = loadB_lds(keyb, 2, l15, quad); k2 = mfma1(a1, B.b1, mfma1(a0, B.b0, k2)); }
    { B2 B = loadB_lds(keyb, 3, l15, quad); k3 = mfma1(a1, B.b1, mfma1(a0, B.b0, k3)); }
    { B2 B = loadB_lds(valb, 0, l15, quad); v0 = mfma1(a1, B.b1, mfma1(a0, B.b0, v0)); }
    { B2 B = loadB_lds(valb, 1, l15, quad); v1 = mfma1(a1, B.b1, mfma1(a0, B.b0, v1)); }
    { B2 B = loadB_lds(valb, 2, l15, quad); v2 = mfma1(a1, B.b1, mfma1(a0, B.b0, v2)); }
    { B2 B = loadB_lds(valb, 3, l15, quad); v3 = mfma1(a1, B.b1, mfma1(a0, B.b0, v3)); }

    f32x4 sv0 = (v0 + vbv[0]) * sc;
    f32x4 sv1 = (v1 + vbv[1]) * sc;
    f32x4 sv2 = (v2 + vbv[2]) * sc;
    f32x4 sv3 = (v3 + vbv[3]) * sc;

    f32x4 mx;
#pragma unroll
    for (int e = 0; e < 4; ++e)
        mx[e] = fmaxf(fmaxf(sv0[e], sv1[e]), fmaxf(sv2[e], sv3[e]));
    red16_max4(mx);
#pragma unroll
    for (int e = 0; e < 4; ++e) {
        sv0[e] = __expf(sv0[e] - mx[e]);
        sv1[e] = __expf(sv1[e] - mx[e]);
        sv2[e] = __expf(sv2[e] - mx[e]);
        sv3[e] = __expf(sv3[e] - mx[e]);
    }
    f32x4 se = sv0 + sv1 + sv2 + sv3;
    red16_sum4(se);

    f32x4 at0 = q0 * (k0 + kbv[0]);
    f32x4 at1 = q1 * (k1 + kbv[1]);
    f32x4 at2 = q2 * (k2 + kbv[2]);
    f32x4 at3 = q3 * (k3 + kbv[3]);
    f32x4 nr = at0 * at0 + at1 * at1 + at2 * at2 + at3 * at3;
    red16_sum4(nr);

    f32x4 fac;
#pragma unroll
    for (int e = 0; e < 4; ++e)
        fac[e] = 1.0f / (fmaxf(sqrtf(nr[e]), 1e-8f) * se[e]);

#pragma unroll
    for (int e = 0; e < 4; ++e) {
        f16_t* rr = Rf + (rtb + quad * 4 + e) * RP16 + l15;
        rr[0]  = (f16_t)(at0[e] * sv0[e] * fac[e]);
        rr[16] = (f16_t)(at1[e] * sv1[e] * fac[e]);
        rr[32] = (f16_t)(at2[e] * sv2[e] * fac[e]);
        rr[48] = (f16_t)(at3[e] * sv3[e] * fac[e]);
    }
}

// 32-row d1 pass: h1 = relu(x @ d1 + b1), relay in-place
__device__ __forceinline__ void d1_rt(f16_t* __restrict__ Rf, const f16_t* __restrict__ wb,
                                      int l15, int quad, int rtb, f32x4 b1v)
{
    f16x8 x00 = *(const f16x8*)(Rf + (rtb + l15) * RP16 + quad * 8);
    f16x8 x01 = *(const f16x8*)(Rf + (rtb + l15) * RP16 + 32 + quad * 8);
    f16x8 x10 = *(const f16x8*)(Rf + (rtb + 16 + l15) * RP16 + quad * 8);
    f16x8 x11 = *(const f16x8*)(Rf + (rtb + 16 + l15) * RP16 + 32 + quad * 8);
    f32x4 h00 = {}, h01 = {}, h02 = {}, h03 = {};
    f32x4 h10 = {}, h11 = {}, h12 = {}, h13 = {};
    GEMML(wb, 0, x00, x01, x10, x11, h00, h10);
    GEMML(wb, 1, x00, x01, x10, x11, h01, h11);
    GEMML(wb, 2, x00, x01, x10, x11, h02, h12);
    GEMML(wb, 3, x00, x01, x10, x11, h03, h13);
#pragma unroll
    for (int e = 0; e < 4; ++e) {
        f16_t* r0 = Rf + (rtb + quad * 4 + e) * RP16 + l15;
        r0[0]  = (f16_t)fmaxf(h00[e] + b1v[0], 0.f);
        r0[16] = (f16_t)fmaxf(h01[e] + b1v[1], 0.f);
        r0[32] = (f16_t)fmaxf(h02[e] + b1v[2], 0.f);
        r0[48] = (f16_t)fmaxf(h03[e] + b1v[3], 0.f);
        f16_t* r1 = Rf + (rtb + 16 + quad * 4 + e) * RP16 + l15;
        r1[0]  = (f16_t)fmaxf(h10[e] + b1v[0], 0.f);
        r1[16] = (f16_t)fmaxf(h11[e] + b1v[1], 0.f);
        r1[32] = (f16_t)fmaxf(h12[e] + b1v[2], 0.f);
        r1[48] = (f16_t)fmaxf(h13[e] + b1v[3], 0.f);
    }
}

// 32-row d2 pass: h2 = relu(h1 @ d2 + b2), 32 cols
__device__ __forceinline__ void d2_rt(f16_t* __restrict__ Rf, const f16_t* __restrict__ wb,
                                      int l15, int quad, int rtb, float b20, float b21)
{
    f16x8 x00 = *(const f16x8*)(Rf + (rtb + l15) * RP16 + quad * 8);
    f16x8 x01 = *(const f16x8*)(Rf + (rtb + l15) * RP16 + 32 + quad * 8);
    f16x8 x10 = *(const f16x8*)(Rf + (rtb + 16 + l15) * RP16 + quad * 8);
    f16x8 x11 = *(const f16x8*)(Rf + (rtb + 16 + l15) * RP16 + 32 + quad * 8);
    f32x4 g00 = {}, g01 = {}, g10 = {}, g11 = {};
    GEMML(wb, 0, x00, x01, x10, x11, g00, g10);
    GEMML(wb, 1, x00, x01, x10, x11, g01, g11);
#pragma unroll
    for (int e = 0; e < 4; ++e) {
        f16_t* r0 = Rf + (rtb + quad * 4 + e) * RP16 + l15;
        r0[0]  = (f16_t)fmaxf(g00[e] + b20, 0.f);
        r0[16] = (f16_t)fmaxf(g01[e] + b21, 0.f);
        f16_t* r1 = Rf + (rtb + 16 + quad * 4 + e) * RP16 + l15;
        r1[0]  = (f16_t)fmaxf(g10[e] + b20, 0.f);
        r1[16] = (f16_t)fmaxf(g11[e] + b21, 0.f);
    }
}

// 32-row d3 pass: out = h2 @ d3 + b3 (K=32) -> two 16-row staged stores.
__device__ __forceinline__ void d3_rt(f16_t* __restrict__ Rf, float* __restrict__ Of,
                                      const char* __restrict__ d3b,
                                      int l15, int quad, int lane, int rtb,
                                      f32x4 b3v, float* __restrict__ obase)
{
    f16x8 a30 = *(const f16x8*)(Rf + (rtb + l15) * RP16 + quad * 8);
    f16x8 a31 = *(const f16x8*)(Rf + (rtb + 16 + l15) * RP16 + quad * 8);
    const int sw3 = ((l15 >> 1) & 3) << 4;
#pragma unroll
    for (int h = 0; h < 2; ++h) {
        const f16x8 a3 = h ? a31 : a30;
#pragma unroll
        for (int c = 0; c < 4; ++c) {
            int o3 = (16 * c + l15) * 64 + quad * 16;
            f16x8 bw = *(const f16x8*)(d3b + (o3 ^ sw3));
            f32x4 z = {};
            f32x4 o = mfma1(a3, bw, z);
#pragma unroll
            for (int e = 0; e < 4; ++e)
                Of[(quad * 4 + e) * OP32 + 16 * c + l15] = o[e] + b3v[c];
        }
#pragma unroll
        for (int i = 0; i < 4; ++i) {
            const int r4 = i * 4 + quad;
            f32x4 v = *(const f32x4*)(Of + r4 * OP32 + l15 * 4);
            *(f32x4*)(obase + rtb * 64 + h * 1024 + i * 256 + lane * 4) = v;
        }
    }
}

// ------- main: PERSISTENT WEIGHTS. 1 block/CU, 8 waves, weights staged into
// LDS ONCE (single barrier); main loop has ZERO barriers, ZERO staging, ZERO
// buffer reuse — waves fully decoupled. Next tile's kv/q' reg-prefetched. ----
__global__ __launch_bounds__(TPB, 2)
void fused_mfma(const float* __restrict__ kv_in, const float* __restrict__ q_in,
                const float* __restrict__ keyB,  const float* __restrict__ valB,
                const float* __restrict__ d1B,   const float* __restrict__ d2B,
                const float* __restrict__ d3B,   const float* __restrict__ scale_p,
                const f16_t* __restrict__ wsf,   float* __restrict__ out)
{
    __shared__ __align__(16) f16_t Wlds[WTOT];              // 98304 B (resident weights)
    __shared__ __align__(16) unsigned char Slab[8][SLABB];  // 36864 B (wave-private)
    __shared__ __align__(16) f16_t Qs16[8][32][8];          // 4096 B  -> 139264 total

    const int tid  = threadIdx.x;
    const int wv   = tid >> 6, lane = tid & 63;
    const int quad = lane >> 4, l15 = lane & 15;
    const long t0  = (long)blockIdx.x * (MT * TILES);

    f16_t* __restrict__ Rf = (f16_t*)Slab[wv];
    float* __restrict__ Of = (float*)Slab[wv];
    const int r = lane >> 1, half = lane & 1;

    // ---- issue tile-0 kv loads FIRST (oldest in vmcnt: consumable while the
    // weight DMA is still in flight via counted waits) ----
    const float4* p40 = (const float4*)(kv_in + (t0 + wv * 32 + r) * 64 + half * 32);
    float4 kf0 = p40[0], kf1 = p40[1], kf2 = p40[2], kf3 = p40[3],
           kf4 = p40[4], kf5 = p40[5], kf6 = p40[6], kf7 = p40[7];
    // tile-0 q' (7 scalar loads; rows are 28B — not 16B-aligned, no float4)
    float qv0 = 0, qv1 = 0, qv2 = 0, qv3 = 0, qv4 = 0, qv5 = 0, qv6 = 0;
    if (lane < 32) {
        const float* qp = q_in + (t0 + wv * 32 + lane) * 7;
        qv0 = qp[0]; qv1 = qp[1]; qv2 = qp[2]; qv3 = qp[3];
        qv4 = qp[4]; qv5 = qp[5]; qv6 = qp[6];
    }

    // ---- ONE-TIME weight DMA (96KB) ----
    stage_all(wsf, Wlds, tid);

    // ---- params (L2 hits, consumed late) ----
    f32x4 kbv, vbv, b1v, b3v;
#pragma unroll
    for (int c = 0; c < 4; ++c) {
        kbv[c] = keyB[16 * c + l15];  vbv[c] = valB[16 * c + l15];
        b1v[c] = d1B[16 * c + l15];   b3v[c] = d3B[16 * c + l15];
    }
    const float b20 = d2B[l15], b21 = d2B[16 + l15];
    const float sc = scale_p[0];

    const f16_t* KEYp = Wlds + OFF_KEY;
    const f16_t* VALp = Wlds + OFF_VAL;
    const f16_t* D1p  = Wlds + OFF_D1;
    const f16_t* D2p  = Wlds + OFF_D2;
    const char*  d3b  = (const char*)(Wlds + OFF_D3);

#pragma unroll 1
    for (int t = 0; t < TILES; ++t) {
        // ---- kv regs -> relay slab (compiler emits counted vmcnt for kf*) ----
        {
            f16_t* dst = Rf + r * RP16 + half * 32;
            f16x8 h;
            h[0]=(f16_t)kf0.x; h[1]=(f16_t)kf0.y; h[2]=(f16_t)kf0.z; h[3]=(f16_t)kf0.w;
            h[4]=(f16_t)kf1.x; h[5]=(f16_t)kf1.y; h[6]=(f16_t)kf1.z; h[7]=(f16_t)kf1.w;
            *(f16x8*)(dst + 0) = h;
            h[0]=(f16_t)kf2.x; h[1]=(f16_t)kf2.y; h[2]=(f16_t)kf2.z; h[3]=(f16_t)kf2.w;
            h[4]=(f16_t)kf3.x; h[5]=(f16_t)kf3.y; h[6]=(f16_t)kf3.z; h[7]=(f16_t)kf3.w;
            *(f16x8*)(dst + 8) = h;
            h[0]=(f16_t)kf4.x; h[1]=(f16_t)kf4.y; h[2]=(f16_t)kf4.z; h[3]=(f16_t)kf4.w;
            h[4]=(f16_t)kf5.x; h[5]=(f16_t)kf5.y; h[6]=(f16_t)kf5.z; h[7]=(f16_t)kf5.w;
            *(f16x8*)(dst + 16) = h;
            h[0]=(f16_t)kf6.x; h[1]=(f16_t)kf6.y; h[2]=(f16_t)kf6.z; h[3]=(f16_t)kf6.w;
            h[4]=(f16_t)kf7.x; h[5]=(f16_t)kf7.y; h[6]=(f16_t)kf7.z; h[7]=(f16_t)kf7.w;
            *(f16x8*)(dst + 24) = h;
        }
        if (lane < 32) {
            f16x8 qh;
            qh[0]=(f16_t)qv0; qh[1]=(f16_t)qv1; qh[2]=(f16_t)qv2; qh[3]=(f16_t)qv3;
            qh[4]=(f16_t)qv4; qh[5]=(f16_t)qv5; qh[6]=(f16_t)qv6; qh[7]=(f16_t)1.0f;
            *(f16x8*)&Qs16[wv][lane][0] = qh;
        }
        // ---- A-fragments (wave-private slab; lgkm-ordered after writes) ----
        f16x8 ah00 = *(const f16x8*)(Rf + l15 * RP16 + quad * 8);
        f16x8 ah01 = *(const f16x8*)(Rf + l15 * RP16 + 32 + quad * 8);
        f16x8 ah10 = *(const f16x8*)(Rf + (16 + l15) * RP16 + quad * 8);
        f16x8 ah11 = *(const f16x8*)(Rf + (16 + l15) * RP16 + 32 + quad * 8);

        if (t == 0) { VMW0(); BAR(); }   // the ONLY barrier: weights resident

        // ---- reg-prefetch next tile's kv+q' (hides under T/front/d compute) ----
        if (t + 1 < TILES) {
            const float4* pn = (const float4*)(kv_in + (t0 + (t + 1) * MT + wv * 32 + r) * 64 + half * 32);
            kf0 = pn[0]; kf1 = pn[1]; kf2 = pn[2]; kf3 = pn[3];
            kf4 = pn[4]; kf5 = pn[5]; kf6 = pn[6]; kf7 = pn[7];
            if (lane < 32) {
                const float* qp = q_in + (t0 + (t + 1) * MT + wv * 32 + lane) * 7;
                qv0 = qp[0]; qv1 = qp[1]; qv2 = qp[2]; qv3 = qp[3];
                qv4 = qp[4]; qv5 = qp[5]; qv6 = qp[6];
            }
        }

        // ---- T stage as one K=512 GEMM from RESIDENT planes (no waits) ----
        f32x4 q00 = {}, q01 = {}, q02 = {}, q03 = {};
        f32x4 q10 = {}, q11 = {}, q12 = {}, q13 = {};
#pragma unroll 1
        for (int p = 0; p < 8; ++p) {
            const f16_t* tb = Wlds + OFF_T + p * 4096;
            f16_t s0 = Qs16[wv][l15][p];
            f16_t s1 = Qs16[wv][16 + l15][p];
            f16x8 w0 = {s0, s0, s0, s0, s0, s0, s0, s0};
            f16x8 w1 = {s1, s1, s1, s1, s1, s1, s1, s1};
            f16x8 sa00 = ah00 * w0, sa01 = ah01 * w0;
            f16x8 sa10 = ah10 * w1, sa11 = ah11 * w1;
            { B2 B = loadB_lds(tb, 0, l15, quad);
              q00 = mfma1(sa01, B.b1, mfma1(sa00, B.b0, q00));
              q10 = mfma1(sa11, B.b1, mfma1(sa10, B.b0, q10)); }
            { B2 B = loadB_lds(tb, 1, l15, quad);
              q01 = mfma1(sa01, B.b1, mfma1(sa00, B.b0, q01));
              q11 = mfma1(sa11, B.b1, mfma1(sa10, B.b0, q11)); }
            { B2 B = loadB_lds(tb, 2, l15, quad);
              q02 = mfma1(sa01, B.b1, mfma1(sa00, B.b0, q02));
              q12 = mfma1(sa11, B.b1, mfma1(sa10, B.b0, q12)); }
            { B2 B = loadB_lds(tb, 3, l15, quad);
              q03 = mfma1(sa01, B.b1, mfma1(sa00, B.b0, q03));
              q13 = mfma1(sa11, B.b1, mfma1(sa10, B.b0, q13)); }
        }

        // ---- fronts: 2 row-tiles (resident KEY/VAL) ----
        front_rt(Rf, KEYp, VALp, l15, quad, 0,  ah00, ah01, q00, q01, q02, q03, kbv, vbv, sc);
        front_rt(Rf, KEYp, VALp, l15, quad, 16, ah10, ah11, q10, q11, q12, q13, kbv, vbv, sc);

        // ---- d-chain (resident D1/D2/D3), then coalesced stores ----
        d1_rt(Rf, D1p, l15, quad, 0, b1v);
        d2_rt(Rf, D2p, l15, quad, 0, b20, b21);
        float* __restrict__ obase = out + (t0 + t * MT + wv * 32) * 64;
        d3_rt(Rf, Of, d3b, l15, quad, lane, 0, b3v, obase);
    }
}

extern "C" void kernel_launch(void* const* d_in, const int* in_sizes, int n_in,
                              void* d_out, int out_size, void* d_ws, size_t ws_size,
                              hipStream_t stream) {
    (void)in_sizes; (void)n_in; (void)out_size; (void)ws_size;
    const float* kv_in = (const float*)d_in[0];
    const float* q_in  = (const float*)d_in[1];
    const float* keyW  = (const float*)d_in[2];
    const float* keyB  = (const float*)d_in[3];
    const float* valW  = (const float*)d_in[4];
    const float* valB  = (const float*)d_in[5];
    const float* TW    = (const float*)d_in[6];
    const float* TB    = (const float*)d_in[7];
    const float* d1W   = (const float*)d_in[8];
    const float* d1B   = (const float*)d_in[9];
    const float* d2W   = (const float*)d_in[10];
    const float* d2B   = (const float*)d_in[11];
    const float* d3W   = (const float*)d_in[12];
    const float* d3B   = (const float*)d_in[13];
    const float* scale = (const float*)d_in[14];
    f16_t* wsf = (f16_t*)d_ws;
    float* outp = (float*)d_out;

    prep_w<<<(WTOT + 255) / 256, 256, 0, stream>>>(keyW, valW, TW, TB, d1W, d2W, d3W, wsf);
    fused_mfma<<<NBLK, TPB, 0, stream>>>(kv_in, q_in, keyB, valB,
                                         d1B, d2B, d3B, scale, wsf, outp);
}

// Round 12
// 128.891 us; speedup vs baseline: 1.0533x; 1.0449x over previous
//
#include <hip/hip_runtime.h>
#include <math.h>

typedef _Float16 f16_t;
typedef __attribute__((ext_vector_type(8))) _Float16 f16x8;
typedef __attribute__((ext_vector_type(4))) float f32x4;

#define NTOK 131072
#define MT   128      // tokens per block
#define TPB  128      // 2 waves; each wave owns 64 tokens (M=64 tile)
#define RP16 72       // relay pitch (f16)
#define SLABB 9216    // per-wave slab: relay 64*72*2

// ws layout (f16 elems)
#define OFF_KEY 0
#define OFF_VAL 4096
#define OFF_T   8192
#define OFF_D1  40960
#define OFF_D2  45056
#define OFF_D3  47104
#define WTOT    49152

__device__ __forceinline__ f32x4 mfma1(f16x8 a, f16x8 b, f32x4 c) {
    return __builtin_amdgcn_mfma_f32_16x16x32_f16(a, b, c, 0, 0, 0);
}

// ---- DPP 16-lane butterfly reductions (VALU, no LDS round-trips) ----------
#define DPPF(x, C) __int_as_float(__builtin_amdgcn_update_dpp( \
    0, __float_as_int(x), (C), 0xF, 0xF, true))

__device__ __forceinline__ void red16_sum4(f32x4& x) {
#pragma unroll
    for (int e = 0; e < 4; ++e) {
        float v = x[e];
        v += DPPF(v, 0xB1);
        v += DPPF(v, 0x4E);
        v += DPPF(v, 0x141);
        v += DPPF(v, 0x140);
        x[e] = v;
    }
}
__device__ __forceinline__ void red16_max4(f32x4& x) {
#pragma unroll
    for (int e = 0; e < 4; ++e) {
        float v = x[e];
        v = fmaxf(v, DPPF(v, 0xB1));
        v = fmaxf(v, DPPF(v, 0x4E));
        v = fmaxf(v, DPPF(v, 0x141));
        v = fmaxf(v, DPPF(v, 0x140));
        x[e] = v;
    }
}

struct B2 { f16x8 b0, b1; };

// LDS B-fragment read, XOR-swizzled (128B-row panels). Proven conflict-clean in R3.
__device__ __forceinline__ B2 loadB_lds(const f16_t* __restrict__ b, int c, int l15, int quad) {
    const char* base = (const char*)b;
    int o0 = (16 * c + l15) * 128 + quad * 16;
    int sw = (l15 & 7) << 4;
    B2 r;
    r.b0 = *(const f16x8*)(base + (o0 ^ sw));
    r.b1 = *(const f16x8*)(base + ((o0 + 64) ^ sw));
    return r;
}

#define GEMML(buf, c, a00, a01, a10, a11, acc0, acc1) do {        \
    B2 Bf = loadB_lds((buf), (c), l15, quad);                      \
    acc0 = mfma1(a01, Bf.b1, mfma1(a00, Bf.b0, acc0));             \
    acc1 = mfma1(a11, Bf.b1, mfma1(a10, Bf.b0, acc1));             \
} while (0)

// async global->LDS DMA, 16B/lane; LDS dest = wave-uniform base + lane*16
__device__ __forceinline__ void gl_lds16(const void* g, void* l) {
    __builtin_amdgcn_global_load_lds(
        (const __attribute__((address_space(1))) unsigned int*)g,
        (__attribute__((address_space(3))) unsigned int*)l, 16, 0, 0);
}

// Stage an 8KB 128B-row panel (TPB=128 -> 4 loads/thread). Swizzle applied as
// inverse perm on the GLOBAL src: LDS[row][col ^ ((row&7)<<4)] = G[row][col].
__device__ __forceinline__ void stage8k(const f16_t* __restrict__ gsrc, f16_t* lbuf, int tid) {
#pragma unroll
    for (int i = 0; i < 4; ++i) {
        int o = (i * TPB + tid) * 16;
        int g = o ^ (((o >> 7) & 7) << 4);
        gl_lds16((const char*)gsrc + g, (char*)lbuf + (o & ~1023));
    }
}
__device__ __forceinline__ void stage4k_r128(const f16_t* __restrict__ gsrc, f16_t* lbuf, int tid) {
#pragma unroll
    for (int i = 0; i < 2; ++i) {
        int o = (i * TPB + tid) * 16;
        int g = o ^ (((o >> 7) & 7) << 4);
        gl_lds16((const char*)gsrc + g, (char*)lbuf + (o & ~1023));
    }
}
// 64B-row panel (d3): swizzle XORs bits 4-5 with row>>1
__device__ __forceinline__ void stage4k_r64(const f16_t* __restrict__ gsrc, f16_t* lbuf, int tid) {
#pragma unroll
    for (int i = 0; i < 2; ++i) {
        int o = (i * TPB + tid) * 16;
        int g = o ^ (((o >> 7) & 3) << 4);
        gl_lds16((const char*)gsrc + g, (char*)lbuf + (o & ~1023));
    }
}

// counted vmcnt + raw barrier (NEVER __syncthreads: it drains vmcnt(0))
#define VMW4() asm volatile("s_waitcnt vmcnt(4)" ::: "memory")
#define VMW0() asm volatile("s_waitcnt vmcnt(0)" ::: "memory")
#define BAR()  do { __builtin_amdgcn_s_barrier(); asm volatile("" ::: "memory"); } while (0)
// BUFFER-RELEASE barrier (R8 race fix): bare s_barrier proves DS reads were
// ISSUED, not COMPLETE. Drain lgkmcnt(0) before releasing a buffer for DMA.
#define BARREL() do { asm volatile("s_waitcnt lgkmcnt(0)" ::: "memory"); \
                      __builtin_amdgcn_s_barrier(); \
                      asm volatile("" ::: "memory"); } while (0)

// ---------------- prep: transpose all weights into ws as fp16 --------------
__global__ __launch_bounds__(256)
void prep_w(const float* __restrict__ keyW, const float* __restrict__ valW,
            const float* __restrict__ TW,   const float* __restrict__ TB,
            const float* __restrict__ d1W,  const float* __restrict__ d2W,
            const float* __restrict__ d3W,  f16_t* __restrict__ wsf)
{
    int idx = blockIdx.x * 256 + threadIdx.x;
    if (idx >= WTOT) return;
    float src;
    if (idx < OFF_VAL) {
        int r = idx - OFF_KEY, n = r >> 6, j = r & 63;
        src = keyW[j * 64 + n];
    } else if (idx < OFF_T) {
        int r = idx - OFF_VAL, n = r >> 6, j = r & 63;
        src = valW[j * 64 + n];
    } else if (idx < OFF_D1) {
        int r = idx - OFF_T, p = r >> 12, q = r & 4095;
        src = (p < 7) ? TW[p * 4096 + q] : TB[q];
    } else if (idx < OFF_D2) {
        int r = idx - OFF_D1, n = r >> 6, j = r & 63;
        src = d1W[j * 64 + n];
    } else if (idx < OFF_D3) {
        int r = idx - OFF_D2, n = r >> 6, j = r & 63;
        src = d2W[j * 32 + n];
    } else {
        int r = idx - OFF_D3, n = r >> 5, j = r & 31;
        src = d3W[j * 64 + n];
    }
    wsf[idx] = (f16_t)src;
}

// per-row-tile front: k|v GEMM (LDS-staged) + softmax + att + normalize + relay.
__device__ __forceinline__ void front_rt(
    f16_t* __restrict__ Rf,
    const f16_t* __restrict__ keyb, const f16_t* __restrict__ valb,
    int l15, int quad, int rtb,
    f16x8 a0, f16x8 a1,
    f32x4 q0, f32x4 q1, f32x4 q2, f32x4 q3,
    f32x4 kbv, f32x4 vbv, float sc)
{
    f32x4 k0 = {}, k1 = {}, k2 = {}, k3 = {}, v0 = {}, v1 = {}, v2 = {}, v3 = {};
    { B2 B = loadB_lds(keyb, 0, l15, quad); k0 = mfma1(a1, B.b1, mfma1(a0, B.b0, k0)); }
    { B2 B = loadB_lds(keyb, 1, l15, quad); k1 = mfma1(a1, B.b1, mfma1(a0, B.b0, k1)); }
    { B2 B = loadB_lds(keyb, 2, l15, quad); k2 = mfma1(a1, B.b1, mfma1(a0, B.b0, k2)); }
    { B2 B = loadB_lds(keyb, 3, l15, quad); k3 = mfma1(a1, B.b1, mfma1(a0, B.b0, k3)); }
    { B2 B = loadB_lds(valb, 0, l15, quad); v0 = mfma1(a1, B.b1, mfma1(a0, B.b0, v0)); }
    { B2 B = loadB_lds(valb, 1, l15, quad); v1 = mfma1(a1, B.b1, mfma1(a0, B.b0, v1)); }
    { B2 B = loadB_lds(valb, 2, l15, quad); v2 = mfma1(a1, B.b1, mfma1(a0, B.b0, v2)); }
    { B2 B = loadB_lds(valb, 3, l15, quad); v3 = mfma1(a1, B.b1, mfma1(a0, B.b0, v3)); }

    f32x4 sv0 = (v0 + vbv[0]) * sc;
    f32x4 sv1 = (v1 + vbv[1]) * sc;
    f32x4 sv2 = (v2 + vbv[2]) * sc;
    f32x4 sv3 = (v3 + vbv[3]) * sc;

    f32x4 mx;
#pragma unroll
    for (int e = 0; e < 4; ++e)
        mx[e] = fmaxf(fmaxf(sv0[e], sv1[e]), fmaxf(sv2[e], sv3[e]));
    red16_max4(mx);
#pragma unroll
    for (int e = 0; e < 4; ++e) {
        sv0[e] = __expf(sv0[e] - mx[e]);
        sv1[e] = __expf(sv1[e] - mx[e]);
        sv2[e] = __expf(sv2[e] - mx[e]);
        sv3[e] = __expf(sv3[e] - mx[e]);
    }
    f32x4 se = sv0 + sv1 + sv2 + sv3;
    red16_sum4(se);

    f32x4 at0 = q0 * (k0 + kbv[0]);
    f32x4 at1 = q1 * (k1 + kbv[1]);
    f32x4 at2 = q2 * (k2 + kbv[2]);
    f32x4 at3 = q3 * (k3 + kbv[3]);
    f32x4 nr = at0 * at0 + at1 * at1 + at2 * at2 + at3 * at3;
    red16_sum4(nr);

    f32x4 fac;
#pragma unroll
    for (int e = 0; e < 4; ++e)
        fac[e] = 1.0f / (fmaxf(sqrtf(nr[e]), 1e-8f) * se[e]);

#pragma unroll
    for (int e = 0; e < 4; ++e) {
        f16_t* rr = Rf + (rtb + quad * 4 + e) * RP16 + l15;
        rr[0]  = (f16_t)(at0[e] * sv0[e] * fac[e]);
        rr[16] = (f16_t)(at1[e] * sv1[e] * fac[e]);
        rr[32] = (f16_t)(at2[e] * sv2[e] * fac[e]);
        rr[48] = (f16_t)(at3[e] * sv3[e] * fac[e]);
    }
}

// 32-row d1 pass: h1 = relu(x @ d1 + b1), relay in-place
__device__ __forceinline__ void d1_rt(f16_t* __restrict__ Rf, const f16_t* __restrict__ wb,
                                      int l15, int quad, int rtb, f32x4 b1v)
{
    f16x8 x00 = *(const f16x8*)(Rf + (rtb + l15) * RP16 + quad * 8);
    f16x8 x01 = *(const f16x8*)(Rf + (rtb + l15) * RP16 + 32 + quad * 8);
    f16x8 x10 = *(const f16x8*)(Rf + (rtb + 16 + l15) * RP16 + quad * 8);
    f16x8 x11 = *(const f16x8*)(Rf + (rtb + 16 + l15) * RP16 + 32 + quad * 8);
    f32x4 h00 = {}, h01 = {}, h02 = {}, h03 = {};
    f32x4 h10 = {}, h11 = {}, h12 = {}, h13 = {};
    GEMML(wb, 0, x00, x01, x10, x11, h00, h10);
    GEMML(wb, 1, x00, x01, x10, x11, h01, h11);
    GEMML(wb, 2, x00, x01, x10, x11, h02, h12);
    GEMML(wb, 3, x00, x01, x10, x11, h03, h13);
#pragma unroll
    for (int e = 0; e < 4; ++e) {
        f16_t* r0 = Rf + (rtb + quad * 4 + e) * RP16 + l15;
        r0[0]  = (f16_t)fmaxf(h00[e] + b1v[0], 0.f);
        r0[16] = (f16_t)fmaxf(h01[e] + b1v[1], 0.f);
        r0[32] = (f16_t)fmaxf(h02[e] + b1v[2], 0.f);
        r0[48] = (f16_t)fmaxf(h03[e] + b1v[3], 0.f);
        f16_t* r1 = Rf + (rtb + 16 + quad * 4 + e) * RP16 + l15;
        r1[0]  = (f16_t)fmaxf(h10[e] + b1v[0], 0.f);
        r1[16] = (f16_t)fmaxf(h11[e] + b1v[1], 0.f);
        r1[32] = (f16_t)fmaxf(h12[e] + b1v[2], 0.f);
        r1[48] = (f16_t)fmaxf(h13[e] + b1v[3], 0.f);
    }
}

// 32-row d2 pass: h2 = relu(h1 @ d2 + b2), 32 cols
__device__ __forceinline__ void d2_rt(f16_t* __restrict__ Rf, const f16_t* __restrict__ wb,
                                      int l15, int quad, int rtb, float b20, float b21)
{
    f16x8 x00 = *(const f16x8*)(Rf + (rtb + l15) * RP16 + quad * 8);
    f16x8 x01 = *(const f16x8*)(Rf + (rtb + l15) * RP16 + 32 + quad * 8);
    f16x8 x10 = *(const f16x8*)(Rf + (rtb + 16 + l15) * RP16 + quad * 8);
    f16x8 x11 = *(const f16x8*)(Rf + (rtb + 16 + l15) * RP16 + 32 + quad * 8);
    f32x4 g00 = {}, g01 = {}, g10 = {}, g11 = {};
    GEMML(wb, 0, x00, x01, x10, x11, g00, g10);
    GEMML(wb, 1, x00, x01, x10, x11, g01, g11);
#pragma unroll
    for (int e = 0; e < 4; ++e) {
        f16_t* r0 = Rf + (rtb + quad * 4 + e) * RP16 + l15;
        r0[0]  = (f16_t)fmaxf(g00[e] + b20, 0.f);
        r0[16] = (f16_t)fmaxf(g01[e] + b21, 0.f);
        f16_t* r1 = Rf + (rtb + 16 + quad * 4 + e) * RP16 + l15;
        r1[0]  = (f16_t)fmaxf(g10[e] + b20, 0.f);
        r1[16] = (f16_t)fmaxf(g11[e] + b21, 0.f);
    }
}

// 32-row d3 pass: out = h2 @ d3 + b3 (K=32) -> DIRECT global stores.
// C layout: row = quad*4+e, col = 16c+l15 -> per-instr 4 x 64B contiguous
// segments (rows quad*4+e, cols 16c..16c+15): consecutive instrs cover full
// cache lines; no LDS Of round-trip (-64 ds_write -8 ds_read per wave-tile).
__device__ __forceinline__ void d3_rt(f16_t* __restrict__ Rf,
                                      const char* __restrict__ d3b,
                                      int l15, int quad, int rtb,
                                      f32x4 b3v, float* __restrict__ obase)
{
    f16x8 a30 = *(const f16x8*)(Rf + (rtb + l15) * RP16 + quad * 8);
    f16x8 a31 = *(const f16x8*)(Rf + (rtb + 16 + l15) * RP16 + quad * 8);
    const int sw3 = ((l15 >> 1) & 3) << 4;
#pragma unroll
    for (int h = 0; h < 2; ++h) {
        const f16x8 a3 = h ? a31 : a30;
#pragma unroll
        for (int c = 0; c < 4; ++c) {
            int o3 = (16 * c + l15) * 64 + quad * 16;
            f16x8 bw = *(const f16x8*)(d3b + (o3 ^ sw3));
            f32x4 z = {};
            f32x4 o = mfma1(a3, bw, z);
#pragma unroll
            for (int e = 0; e < 4; ++e)
                obase[(rtb + h * 16 + quad * 4 + e) * 64 + 16 * c + l15] = o[e] + b3v[c];
        }
    }
}

// ------- main: R7 structure (M=64, MT=128, TPB=128, 4 blk/CU) + BARREL race
// fix + d3 direct stores. Best-measured config, made correct. -------------
__global__ __launch_bounds__(TPB, 2)   // natural regalloc; spill tripwire = WRITE_SIZE
void fused_mfma(const float* __restrict__ kv_in, const float* __restrict__ q_in,
                const float* __restrict__ keyB,  const float* __restrict__ valB,
                const float* __restrict__ d1B,   const float* __restrict__ d2B,
                const float* __restrict__ d3B,   const float* __restrict__ scale_p,
                const f16_t* __restrict__ wsf,   float* __restrict__ out)
{
    __shared__ __align__(16) unsigned char Slab[2][SLABB];   // 18432 B (wave-private)
    __shared__ __align__(16) f16_t Qs16[MT][8];              // 2048 B (f16 q'-table)
    __shared__ __align__(16) f16_t WB[2][4096];              // 16384 B -> 36864 total

    const int tid  = threadIdx.x;
    const int wv   = tid >> 6, lane = tid & 63;
    const int quad = lane >> 4, l15 = lane & 15;
    const int RB   = wv * 64;
    const long t0  = (long)blockIdx.x * MT;

    f16_t* __restrict__ Rf = (f16_t*)Slab[wv];

    // ---- relay FIRST (its vmcnt drain not blocked behind weight DMA) ----
    {
        const int r = lane >> 1, half = lane & 1;
#pragma unroll
        for (int s = 0; s < 2; ++s) {
            const float4* p4 = (const float4*)(kv_in + (t0 + RB + s * 32 + r) * 64 + half * 32);
            f16_t* dst = Rf + (s * 32 + r) * RP16 + half * 32;
#pragma unroll
            for (int b = 0; b < 4; ++b) {
                float4 f0 = p4[2 * b], f1 = p4[2 * b + 1];
                f16x8 h;
                h[0] = (f16_t)f0.x; h[1] = (f16_t)f0.y; h[2] = (f16_t)f0.z; h[3] = (f16_t)f0.w;
                h[4] = (f16_t)f1.x; h[5] = (f16_t)f1.y; h[6] = (f16_t)f1.z; h[7] = (f16_t)f1.w;
                *(f16x8*)(dst + 8 * b) = h;
            }
        }
    }
    // q' -> Qs16 as f16 [token][plane] (wave-private rows)
    {
        const float* qp = q_in + (t0 + RB + lane) * 7;
        f16x8 qh;
#pragma unroll
        for (int p = 0; p < 7; ++p) qh[p] = (f16_t)qp[p];
        qh[7] = (f16_t)1.0f;
        *(f16x8*)&Qs16[RB + lane][0] = qh;
    }
    // small params (L2 hits, consumed late)
    f32x4 kbv, vbv, b1v, b3v;
#pragma unroll
    for (int c = 0; c < 4; ++c) {
        kbv[c] = keyB[16 * c + l15];  vbv[c] = valB[16 * c + l15];
        b1v[c] = d1B[16 * c + l15];   b3v[c] = d3B[16 * c + l15];
    }
    const float b20 = d2B[l15], b21 = d2B[16 + l15];
    const float sc = scale_p[0];

    // async DMA of T planes 0,1 (newest in queue -> VMW4 at p=0 waits T0 only)
    stage8k(wsf + OFF_T + 0 * 4096, WB[0], tid);
    stage8k(wsf + OFF_T + 1 * 4096, WB[1], tid);

    // ---- A-fragments: 4 row-tiles x 2 halves (named) ----
    f16x8 ah00 = *(const f16x8*)(Rf + l15 * RP16 + quad * 8);
    f16x8 ah01 = *(const f16x8*)(Rf + l15 * RP16 + 32 + quad * 8);
    f16x8 ah10 = *(const f16x8*)(Rf + (16 + l15) * RP16 + quad * 8);
    f16x8 ah11 = *(const f16x8*)(Rf + (16 + l15) * RP16 + 32 + quad * 8);
    f16x8 ah20 = *(const f16x8*)(Rf + (32 + l15) * RP16 + quad * 8);
    f16x8 ah21 = *(const f16x8*)(Rf + (32 + l15) * RP16 + 32 + quad * 8);
    f16x8 ah30 = *(const f16x8*)(Rf + (48 + l15) * RP16 + quad * 8);
    f16x8 ah31 = *(const f16x8*)(Rf + (48 + l15) * RP16 + 32 + quad * 8);

    // ---- T stage as one K=512 GEMM, 2-buffer pipeline ----
    // iter p: VMW4 (plane p landed; plane p+1's 4 loads in flight); BAR;
    // compute from WB[p&1]; BARREL (DS reads COMPLETE, all waves);
    // stage plane p+2 into WB[p&1].
    f32x4 q00 = {}, q01 = {}, q02 = {}, q03 = {};
    f32x4 q10 = {}, q11 = {}, q12 = {}, q13 = {};
    f32x4 q20 = {}, q21 = {}, q22 = {}, q23 = {};
    f32x4 q30 = {}, q31 = {}, q32 = {}, q33 = {};
#pragma unroll 1
    for (int p = 0; p < 8; ++p) {
        const f16_t* tb = WB[p & 1];
        VMW4(); BAR();
        // per-row-tile q' scales (quad-broadcast ds_read_u16, wave-private)
        f16_t s0 = Qs16[RB + l15][p];
        f16_t s1 = Qs16[RB + 16 + l15][p];
        f16_t s2 = Qs16[RB + 32 + l15][p];
        f16_t s3 = Qs16[RB + 48 + l15][p];
        f16x8 w0 = {s0, s0, s0, s0, s0, s0, s0, s0};
        f16x8 w1 = {s1, s1, s1, s1, s1, s1, s1, s1};
        f16x8 w2 = {s2, s2, s2, s2, s2, s2, s2, s2};
        f16x8 w3 = {s3, s3, s3, s3, s3, s3, s3, s3};
        f16x8 sa00 = ah00 * w0, sa01 = ah01 * w0;
        f16x8 sa10 = ah10 * w1, sa11 = ah11 * w1;
        f16x8 sa20 = ah20 * w2, sa21 = ah21 * w2;
        f16x8 sa30 = ah30 * w3, sa31 = ah31 * w3;
        { B2 B = loadB_lds(tb, 0, l15, quad);
          q00 = mfma1(sa01, B.b1, mfma1(sa00, B.b0, q00));
          q10 = mfma1(sa11, B.b1, mfma1(sa10, B.b0, q10));
          q20 = mfma1(sa21, B.b1, mfma1(sa20, B.b0, q20));
          q30 = mfma1(sa31, B.b1, mfma1(sa30, B.b0, q30)); }
        { B2 B = loadB_lds(tb, 1, l15, quad);
          q01 = mfma1(sa01, B.b1, mfma1(sa00, B.b0, q01));
          q11 = mfma1(sa11, B.b1, mfma1(sa10, B.b0, q11));
          q21 = mfma1(sa21, B.b1, mfma1(sa20, B.b0, q21));
          q31 = mfma1(sa31, B.b1, mfma1(sa30, B.b0, q31)); }
        { B2 B = loadB_lds(tb, 2, l15, quad);
          q02 = mfma1(sa01, B.b1, mfma1(sa00, B.b0, q02));
          q12 = mfma1(sa11, B.b1, mfma1(sa10, B.b0, q12));
          q22 = mfma1(sa21, B.b1, mfma1(sa20, B.b0, q22));
          q32 = mfma1(sa31, B.b1, mfma1(sa30, B.b0, q32)); }
        { B2 B = loadB_lds(tb, 3, l15, quad);
          q03 = mfma1(sa01, B.b1, mfma1(sa00, B.b0, q03));
          q13 = mfma1(sa11, B.b1, mfma1(sa10, B.b0, q13));
          q23 = mfma1(sa21, B.b1, mfma1(sa20, B.b0, q23));
          q33 = mfma1(sa31, B.b1, mfma1(sa30, B.b0, q33)); }
        BARREL();   // release WB[p&1] for overwrite (reads drained, all waves)
        const f16_t* nsrc = (p < 6) ? (wsf + OFF_T + (p + 2) * 4096)
                                    : ((p == 6) ? (wsf + OFF_KEY) : (wsf + OFF_VAL));
        stage8k(nsrc, WB[p & 1], tid);
    }
    VMW0(); BAR();   // KEY in WB[0], VAL in WB[1] ready

    // ---- fronts: 4 independent row-tiles (k|v + softmax + att + relay) ----
    front_rt(Rf, WB[0], WB[1], l15, quad, 0,  ah00, ah01, q00, q01, q02, q03, kbv, vbv, sc);
    front_rt(Rf, WB[0], WB[1], l15, quad, 16, ah10, ah11, q10, q11, q12, q13, kbv, vbv, sc);
    front_rt(Rf, WB[0], WB[1], l15, quad, 32, ah20, ah21, q20, q21, q22, q23, kbv, vbv, sc);
    front_rt(Rf, WB[0], WB[1], l15, quad, 48, ah30, ah31, q30, q31, q32, q33, kbv, vbv, sc);
    BARREL();        // release KEY/VAL panels (reads drained, all waves)
    stage8k(wsf + OFF_D1, WB[0], tid);                 // d1 -> WB[0] (8KB)
    stage4k_r128(wsf + OFF_D2, WB[1], tid);            // d2 -> WB[1][0:2048] (4KB)
    stage4k_r64 (wsf + OFF_D3, WB[1] + 2048, tid);     // d3 -> WB[1][2048:] (4KB, 64B rows)
    VMW0(); BAR();

    // ---- d-chain: two 32-row passes per layer (wave-private, no barriers) ----
    d1_rt(Rf, WB[0], l15, quad, 0,  b1v);
    d1_rt(Rf, WB[0], l15, quad, 32, b1v);
    d2_rt(Rf, WB[1], l15, quad, 0,  b20, b21);
    d2_rt(Rf, WB[1], l15, quad, 32, b20, b21);

    float* __restrict__ obase = out + (t0 + RB) * 64;
    const char* d3b = (const char*)(&WB[1][2048]);
    d3_rt(Rf, d3b, l15, quad, 0,  b3v, obase);
    d3_rt(Rf, d3b, l15, quad, 32, b3v, obase);
}

extern "C" void kernel_launch(void* const* d_in, const int* in_sizes, int n_in,
                              void* d_out, int out_size, void* d_ws, size_t ws_size,
                              hipStream_t stream) {
    (void)in_sizes; (void)n_in; (void)out_size; (void)ws_size;
    const float* kv_in = (const float*)d_in[0];
    const float* q_in  = (const float*)d_in[1];
    const float* keyW  = (const float*)d_in[2];
    const float* keyB  = (const float*)d_in[3];
    const float* valW  = (const float*)d_in[4];
    const float* valB  = (const float*)d_in[5];
    const float* TW    = (const float*)d_in[6];
    const float* TB    = (const float*)d_in[7];
    const float* d1W   = (const float*)d_in[8];
    const float* d1B   = (const float*)d_in[9];
    const float* d2W   = (const float*)d_in[10];
    const float* d2B   = (const float*)d_in[11];
    const float* d3W   = (const float*)d_in[12];
    const float* d3B   = (const float*)d_in[13];
    const float* scale = (const float*)d_in[14];
    f16_t* wsf = (f16_t*)d_ws;
    float* outp = (float*)d_out;

    prep_w<<<(WTOT + 255) / 256, 256, 0, stream>>>(keyW, valW, TW, TB, d1W, d2W, d3W, wsf);
    fused_mfma<<<NTOK / MT, TPB, 0, stream>>>(kv_in, q_in, keyB, valB,
                                              d1B, d2B, d3B, scale, wsf, outp);
}